// Round 9
// baseline (221.129 us; speedup 1.0000x reference)
//
#include <hip/hip_runtime.h>
#include <hip/hip_bf16.h>

// 2-layer GCN on MI355X.
// R14. R13 post-mortem: zero-LDS fusion null AGAIN (fused = 56 ≈ 45+11
// serial) -> no free overlap exists; abandoned. New insight from re-reading
// build: the 4 per-component `if (in-partition)` blocks are EXEC-MASKED
// regions -> compiler cannot hoist atomics across them -> the 4 atomic→store
// chains issue SERIALLY (why R6's ILP prediction failed). Partition rescan
// also re-reads dst 8x (FETCH 38MB).
// R14 change (single variable): branchless single-pass build, ONE EDGE PER
// THREAD. No partitions, no loop, no branches: 2 coalesced loads ->
// unconditional atomicAdd -> 2B store. 800K independent chains; limited only
// by L2/fabric RMW rate. Build blocks FIRST in fused grid, gemm1 trails.
// Predict: fused 56 -> 22-30us (latency-wall theory) => total ~172-182;
// if flat ~50-56 => build is at machine roofline -> harvest agg2/gemm2 next.

#define ELL_CAP 64   // deg ~ Poisson(16); P(deg>=64) ~ 1e-18

typedef __attribute__((ext_vector_type(8))) short short8;   // 8 bf16 (4 VGPRs)
typedef __attribute__((ext_vector_type(4))) float f32x4;

static __device__ __forceinline__ unsigned short f2bf(float f) {
    unsigned int u = __float_as_uint(f);
    u = (u + 0x7fff + ((u >> 16) & 1)) >> 16;   // round-to-nearest-even
    return (unsigned short)u;
}
static __device__ __forceinline__ float2 bfunpack(unsigned int u) {
    return make_float2(__uint_as_float(u << 16),            // low short  = feat 2i
                       __uint_as_float(u & 0xffff0000u));   // high short = feat 2i+1
}

// ---------------- init: cnt zeroing + both weight transposes ----------------

__global__ void init_misc(const float* __restrict__ W1, const float* __restrict__ W2,
                          short* __restrict__ w1t, short* __restrict__ w2t,
                          int* __restrict__ cnt, int n)
{
    int i = blockIdx.x * blockDim.x + threadIdx.x;
    if (i < 128 * 128) {
        int k = i >> 7, nn = i & 127;
        w1t[nn * 128 + k] = (short)f2bf(W1[i]);
    } else if (i < 128 * 128 + 128 * 64) {
        int j = i - 128 * 128;
        int k = j >> 6, nn = j & 63;
        w2t[nn * 128 + k] = (short)f2bf(W2[j]);
    }
    if (i < n) cnt[i] = 0;
}

// ---------------- fused: branchless ELL build (first) + zero-LDS gemm1 -----
// blocks [0, nBuild):          build, one edge per thread, no branches
// blocks [nBuild, nBuild+782): gemm1 (no LDS): h1b = bf16(x @ W1), UNSCALED

__global__ __launch_bounds__(256) void fused_b_g1(
    const float* __restrict__ x, const short* __restrict__ w1t,
    const int* __restrict__ src, const int* __restrict__ dst,
    int* __restrict__ cnt, unsigned short* __restrict__ ell,
    unsigned short* __restrict__ h1b, int n, int E, int nBuild)
{
    const int bid = blockIdx.x;
    const int tid = threadIdx.x;

    if (bid < nBuild) {
        // ---- branchless build: one edge per thread ----
        int e = bid * 256 + tid;
        if (e < E) {
            int d = dst[e];                        // coalesced dword
            int s = src[e];                        // coalesced dword
            int p = atomicAdd(&cnt[d], 1);         // unconditional, device-scope
            if (p < ELL_CAP)                       // ~never taken branch-out
                ell[(size_t)d * ELL_CAP + p] = (unsigned short)s;
        }
        return;
    }

    // ---- gemm1, zero-LDS: B fragments streamed from w1t (32KB, L2-hot) ----
    const int gb = bid - nBuild;
    const int wave = tid >> 6, lane = tid & 63;
    const int row0 = gb * 64 + wave * 16;
    if (row0 >= n) return;
    const int quad = lane >> 4, l16 = lane & 15;

    short8 af[4];
    {
        const float* arow = x + (size_t)(row0 + l16) * 128 + quad * 8;
        #pragma unroll
        for (int kk = 0; kk < 4; ++kk) {
            float4 u = *(const float4*)(arow + kk * 32);
            float4 v = *(const float4*)(arow + kk * 32 + 4);
            short8 f;
            f[0] = (short)f2bf(u.x); f[1] = (short)f2bf(u.y);
            f[2] = (short)f2bf(u.z); f[3] = (short)f2bf(u.w);
            f[4] = (short)f2bf(v.x); f[5] = (short)f2bf(v.y);
            f[6] = (short)f2bf(v.z); f[7] = (short)f2bf(v.w);
            af[kk] = f;
        }
    }

    #pragma unroll
    for (int t = 0; t < 8; ++t) {
        f32x4 acc = {0.f, 0.f, 0.f, 0.f};
        #pragma unroll
        for (int kk = 0; kk < 4; ++kk) {
            short8 bfr = *(const short8*)(w1t + (t * 16 + l16) * 128 + kk * 32 + quad * 8);
            acc = __builtin_amdgcn_mfma_f32_16x16x32_bf16(af[kk], bfr, acc, 0, 0, 0);
        }
        #pragma unroll
        for (int r = 0; r < 4; ++r) {
            int gr = row0 + quad * 4 + r;
            h1b[(size_t)gr * 128 + t * 16 + l16] = f2bf(acc[r]);   // UNSCALED
        }
    }
}

// ---------------- MFMA GEMM (layer 2, LDS version, unchanged) --------------
// Cb[i][j] = bf16(dinv[i]*(A W)[i][j]); cnt final here.

template<int NC>
__global__ __launch_bounds__(256) void gemm_mfma(
    const short* __restrict__ A, const short* __restrict__ Bt,
    const int* __restrict__ cnt, unsigned short* __restrict__ Cb, int n)
{
    __shared__ short Bs[NC][136];
    const int tid = threadIdx.x;

    #pragma unroll
    for (int i = 0; i < NC / 16; ++i) {
        int idx = tid + i * 256;
        int nrow = idx >> 4;
        int kcol = (idx & 15) * 8;
        *(short8*)&Bs[nrow][kcol] = *(const short8*)(Bt + nrow * 128 + kcol);
    }
    __syncthreads();

    const int wave = tid >> 6, lane = tid & 63;
    const int row0 = blockIdx.x * 64 + wave * 16;
    if (row0 >= n) return;
    const int quad = lane >> 4, l16 = lane & 15;

    short8 af[4];
    {
        const short* arow = A + (size_t)(row0 + l16) * 128 + quad * 8;
        #pragma unroll
        for (int kk = 0; kk < 4; ++kk)
            af[kk] = *(const short8*)(arow + kk * 32);
    }

    float dv[4];
    #pragma unroll
    for (int r = 0; r < 4; ++r)
        dv[r] = rsqrtf((float)cnt[row0 + quad * 4 + r] + 1.0f);

    #pragma unroll
    for (int t = 0; t < NC / 16; ++t) {
        f32x4 acc = {0.f, 0.f, 0.f, 0.f};
        #pragma unroll
        for (int kk = 0; kk < 4; ++kk) {
            short8 bfr = *(const short8*)&Bs[t * 16 + l16][kk * 32 + quad * 8];
            acc = __builtin_amdgcn_mfma_f32_16x16x32_bf16(af[kk], bfr, acc, 0, 0, 0);
        }
        #pragma unroll
        for (int r = 0; r < 4; ++r) {
            int gr = row0 + quad * 4 + r;
            Cb[(size_t)gr * NC + t * 16 + l16] = f2bf(acc[r] * dv[r]);
        }
    }
}

// ---------------- wide-gather aggregates (unchanged from R13) ----------------
// L1: one wave per node, 256B UNSCALED rows, dwordx4 gather = 4 edges/instr.
// Per-edge dinv[src]: q = rsqrt(cnt[s]+1) masked by validity (1 cndmask).
// MEASURED at 6.2 TB/s effective = gather byte-floor.

__global__ __launch_bounds__(256) void aggregate_l1(
    const unsigned short* __restrict__ hb,   // [n][128] bf16, UNSCALED
    const unsigned short* __restrict__ ell,
    const int* __restrict__ cnt, const float* __restrict__ bias,
    unsigned int* __restrict__ z1b, int n)   // [n][64] bf16x2
{
    const int node = blockIdx.x * 4 + (threadIdx.x >> 6);
    if (node >= n) return;
    const int lane = threadIdx.x & 63;
    const int quad = lane >> 4, l16 = lane & 15;

    int deg = cnt[node];
    const float d = rsqrtf((float)deg + 1.0f);
    if (deg > ELL_CAP) deg = ELL_CAP;
    const unsigned short* __restrict__ row = ell + (size_t)node * ELL_CAP;

    float acc[8];
    {   // self term: q = d on quad 0, else 0 (contributes d^2*h after final *d)
        uint4 v = *(const uint4*)(hb + (size_t)node * 128 + l16 * 8);
        float qs = (quad == 0) ? d : 0.f;
        #pragma unroll
        for (int j = 0; j < 4; ++j) {
            float2 f = bfunpack(((const unsigned int*)&v)[j]);
            acc[2 * j]     = f.x * qs;
            acc[2 * j + 1] = f.y * qs;
        }
    }
    const int degR = (deg + 3) & ~3;
    #pragma unroll 2
    for (int e = 0; e < degR; e += 4) {
        unsigned int w0 = *(const unsigned int*)&row[e];       // edges e,e+1
        unsigned int w1 = *(const unsigned int*)&row[e + 2];   // edges e+2,e+3
        unsigned int hw = (quad & 2) ? w1 : w0;
        int s = (quad & 1) ? (int)(hw >> 16) : (int)(hw & 0xffff);
        s = min(s, n - 1);                                      // poison-safe
        float q = rsqrtf((float)cnt[s] + 1.0f);                 // dinv[src]
        q = (e + quad < deg) ? q : 0.f;                         // 1 cndmask/edge
        uint4 v = *(const uint4*)(hb + (size_t)s * 128 + l16 * 8);
        #pragma unroll
        for (int j = 0; j < 4; ++j) {
            float2 f = bfunpack(((const unsigned int*)&v)[j]);
            acc[2 * j]     = fmaf(f.x, q, acc[2 * j]);
            acc[2 * j + 1] = fmaf(f.y, q, acc[2 * j + 1]);
        }
    }
    #pragma unroll
    for (int j = 0; j < 8; ++j) {            // fold 4 quads
        acc[j] += __shfl_xor(acc[j], 16);
        acc[j] += __shfl_xor(acc[j], 32);
    }
    if (quad == 0) {
        unsigned int ow[4];
        #pragma unroll
        for (int j = 0; j < 4; ++j) {
            float bx = bias[l16 * 8 + 2 * j];
            float by = bias[l16 * 8 + 2 * j + 1];
            float ox = fmaxf(fmaf(acc[2 * j],     d, bx), 0.f);
            float oy = fmaxf(fmaf(acc[2 * j + 1], d, by), 0.f);
            ow[j] = (unsigned int)f2bf(ox) | ((unsigned int)f2bf(oy) << 16);
        }
        *(uint4*)&z1b[(size_t)node * 64 + l16 * 4] = *(const uint4*)ow;
    }
}

// L2: one wave per node, 128B PRE-SCALED rows, dwordx4 gather = 8 edges/instr.

__global__ __launch_bounds__(256) void aggregate_l2(
    const unsigned short* __restrict__ hb,   // [n][64] bf16, dinv-scaled
    const unsigned short* __restrict__ ell,
    const int* __restrict__ cnt, const float* __restrict__ bias,
    float* __restrict__ out, int n)          // [n][64] fp32
{
    const int node = blockIdx.x * 4 + (threadIdx.x >> 6);
    if (node >= n) return;
    const int lane = threadIdx.x & 63;
    const int oct = lane >> 3, l8 = lane & 7;

    int deg = cnt[node];
    const float d = rsqrtf((float)deg + 1.0f);
    if (deg > ELL_CAP) deg = ELL_CAP;
    const unsigned short* __restrict__ row = ell + (size_t)node * ELL_CAP;

    float acc[8];
    {   // self term (oct 0 only)
        uint4 v = *(const uint4*)(hb + (size_t)node * 64 + l8 * 8);
        float ms = (oct == 0) ? 1.f : 0.f;
        #pragma unroll
        for (int j = 0; j < 4; ++j) {
            float2 f = bfunpack(((const unsigned int*)&v)[j]);
            acc[2 * j]     = f.x * ms;
            acc[2 * j + 1] = f.y * ms;
        }
    }
    const int degR = (deg + 7) & ~7;
    #pragma unroll 2
    for (int e = 0; e < degR; e += 8) {
        uint4 w = *(const uint4*)&row[e];    // edges e..e+7
        unsigned int pw = (oct & 4) ? ((oct & 2) ? w.w : w.z)
                                    : ((oct & 2) ? w.y : w.x);
        int s = (oct & 1) ? (int)(pw >> 16) : (int)(pw & 0xffff);
        s = min(s, n - 1);                   // poison-safe
        float m = (e + oct < deg) ? 1.f : 0.f;   // 1 cndmask/edge
        uint4 v = *(const uint4*)(hb + (size_t)s * 64 + l8 * 8);
        #pragma unroll
        for (int j = 0; j < 4; ++j) {
            float2 f = bfunpack(((const unsigned int*)&v)[j]);
            acc[2 * j]     = fmaf(f.x, m, acc[2 * j]);
            acc[2 * j + 1] = fmaf(f.y, m, acc[2 * j + 1]);
        }
    }
    #pragma unroll
    for (int j = 0; j < 8; ++j) {            // fold 8 octs
        acc[j] += __shfl_xor(acc[j], 8);
        acc[j] += __shfl_xor(acc[j], 16);
        acc[j] += __shfl_xor(acc[j], 32);
    }
    if (oct == 0) {
        float* op = out + (size_t)node * 64 + l8 * 8;
        float4 o0, o1;
        o0.x = fmaf(acc[0], d, bias[l8 * 8 + 0]);
        o0.y = fmaf(acc[1], d, bias[l8 * 8 + 1]);
        o0.z = fmaf(acc[2], d, bias[l8 * 8 + 2]);
        o0.w = fmaf(acc[3], d, bias[l8 * 8 + 3]);
        o1.x = fmaf(acc[4], d, bias[l8 * 8 + 4]);
        o1.y = fmaf(acc[5], d, bias[l8 * 8 + 5]);
        o1.z = fmaf(acc[6], d, bias[l8 * 8 + 6]);
        o1.w = fmaf(acc[7], d, bias[l8 * 8 + 7]);
        *(float4*)(op)     = o0;
        *(float4*)(op + 4) = o1;
    }
}

// ---------------- launcher ----------------

extern "C" void kernel_launch(void* const* d_in, const int* in_sizes, int n_in,
                              void* d_out, int out_size, void* d_ws, size_t ws_size,
                              hipStream_t stream)
{
    const float* x  = (const float*)d_in[0];
    const int*   ei = (const int*)d_in[1];   // [2][E] int32
    const float* W1 = (const float*)d_in[2];
    const float* b1 = (const float*)d_in[3];
    const float* W2 = (const float*)d_in[4];
    const float* b2 = (const float*)d_in[5];
    float* out = (float*)d_out;

    const int N = in_sizes[0] / 128;   // 50000
    const int E = in_sizes[1] / 2;     // 800000
    const int* src = ei;
    const int* dst = ei + E;

    char* ws = (char*)d_ws;
    size_t off = 0;
    auto alloc = [&](size_t bytes) -> void* {
        void* p = ws + off;
        off += (bytes + 255) & ~(size_t)255;
        return p;
    };
    int*            cnt  = (int*)           alloc((size_t)N * 4);
    unsigned short* ell  = (unsigned short*)alloc((size_t)N * ELL_CAP * 2);
    short*          w1t  = (short*)         alloc((size_t)128 * 128 * 2);
    short*          w2t  = (short*)         alloc((size_t)64 * 128 * 2);
    unsigned short* h1b  = (unsigned short*)alloc((size_t)N * 128 * 2);  // bf16
    unsigned int*   z1b  = (unsigned int*)  alloc((size_t)N * 64 * 4);   // bf16x2
    unsigned short* h2b  = (unsigned short*)alloc((size_t)N * 64 * 2);   // bf16

    init_misc<<<(N + 255) / 256, 256, 0, stream>>>(W1, W2, w1t, w2t, cnt, N);

    // branchless build (one edge/thread, blocks first) + zero-LDS gemm1 tail
    const int nBuild = (E + 255) / 256;             // 3125
    const int nGemm  = (N + 63) / 64;               // 782
    fused_b_g1<<<nBuild + nGemm, 256, 0, stream>>>(
        x, w1t, src, dst, cnt, ell, h1b, N, E, nBuild);

    aggregate_l1<<<(N + 3) / 4, 256, 0, stream>>>(h1b, ell, cnt, b1, z1b, N);

    gemm_mfma<64><<<(N + 63) / 64, 256, 0, stream>>>(
        (const short*)z1b, w2t, cnt, h2b, N);

    aggregate_l2<<<(N + 3) / 4, 256, 0, stream>>>(h2b, ell, cnt, b2, out, N);
}

// Round 10
// 197.709 us; speedup vs baseline: 1.1185x; 1.1185x over previous
//
#include <hip/hip_runtime.h>
#include <hip/hip_bf16.h>

// 2-layer GCN on MI355X.
// R15. R14 post-mortem: removing XCD partitioning regressed build 45->82us
// (WRITE 42->57MB = cross-XCD dirty-line ping-pong; partitioning is
// load-bearing). But R14's motivating defect is real: in the partitioned
// loop each `if(in){p=atomicAdd;store}` block forces vmcnt(0) INSIDE the
// exec-masked region -> 4 atomic round-trips serialize per iteration.
// R15 (single variable vs R13): split issue/consume. Pass 1 issues the 4
// exec-masked atomics with NO use of p (no wait between them); pass 2 does
// one wait + 4 predicated stores. Atomic count unchanged (800K), XCD
// locality unchanged, 4 round-trips overlap. Build blocks lead the grid.
// Predict: fused 56 -> 40-48 (build ~45->~30), total ~185-190.
// Pre-committed null: fused >= 53 -> build at machine floor -> declare.

#define ELL_CAP 64   // deg ~ Poisson(16); P(deg>=64) ~ 1e-18
#define NPART 8      // = XCD count
#define NBUILD 2048  // 256 chunks x 8 partitions; %8==0 so part = bid&7 = XCD

typedef __attribute__((ext_vector_type(8))) short short8;   // 8 bf16 (4 VGPRs)
typedef __attribute__((ext_vector_type(4))) float f32x4;

static __device__ __forceinline__ unsigned short f2bf(float f) {
    unsigned int u = __float_as_uint(f);
    u = (u + 0x7fff + ((u >> 16) & 1)) >> 16;   // round-to-nearest-even
    return (unsigned short)u;
}
static __device__ __forceinline__ float2 bfunpack(unsigned int u) {
    return make_float2(__uint_as_float(u << 16),            // low short  = feat 2i
                       __uint_as_float(u & 0xffff0000u));   // high short = feat 2i+1
}

// ---------------- init: cnt zeroing + both weight transposes ----------------

__global__ void init_misc(const float* __restrict__ W1, const float* __restrict__ W2,
                          short* __restrict__ w1t, short* __restrict__ w2t,
                          int* __restrict__ cnt, int n)
{
    int i = blockIdx.x * blockDim.x + threadIdx.x;
    if (i < 128 * 128) {
        int k = i >> 7, nn = i & 127;
        w1t[nn * 128 + k] = (short)f2bf(W1[i]);
    } else if (i < 128 * 128 + 128 * 64) {
        int j = i - 128 * 128;
        int k = j >> 6, nn = j & 63;
        w2t[nn * 128 + k] = (short)f2bf(W2[j]);
    }
    if (i < n) cnt[i] = 0;
}

// ---------------- fused: XCD-partitioned build (issue/consume split) -------
// blocks [0, NBUILD):           build (part = bid&7 = XCD, chunk = bid>>3)
// blocks [NBUILD, NBUILD+782):  gemm1 (no LDS): h1b = bf16(x @ W1), UNSCALED

__global__ __launch_bounds__(256) void fused_b_g1(
    const float* __restrict__ x, const short* __restrict__ w1t,
    const int* __restrict__ src, const int* __restrict__ dst,
    int* __restrict__ cnt, unsigned short* __restrict__ ell,
    unsigned short* __restrict__ h1b, int n, int E, int partSize)
{
    const int bid = blockIdx.x;
    const int tid = threadIdx.x;

    if (bid < NBUILD) {
        // ---- ELL build, 4 overlapped atomic chains per iteration ----
        const int part  = bid & (NPART - 1);       // = XCD under round-robin
        const int chunk = bid >> 3;
        const int nchunk = NBUILD >> 3;            // 256
        const int lo = part * partSize, hi = lo + partSize;
        const int E4  = E >> 2;
        const int per = (E4 + nchunk - 1) / nchunk;
        const int i1  = min((chunk + 1) * per, E4);
        const int4* __restrict__ d4p = (const int4*)dst;
        const int4* __restrict__ s4p = (const int4*)src;
        for (int i = chunk * per + tid; i < i1; i += 256) {
            int4 d4 = d4p[i];
            int4 s4 = s4p[i];
            bool v0 = d4.x >= lo && d4.x < hi;
            bool v1 = d4.y >= lo && d4.y < hi;
            bool v2 = d4.z >= lo && d4.z < hi;
            bool v3 = d4.w >= lo && d4.w < hi;
            int p0 = ELL_CAP, p1 = ELL_CAP, p2 = ELL_CAP, p3 = ELL_CAP;
            // issue pass: no use of p -> no vmcnt wait between atomics
            if (v0) p0 = atomicAdd(&cnt[d4.x], 1);
            if (v1) p1 = atomicAdd(&cnt[d4.y], 1);
            if (v2) p2 = atomicAdd(&cnt[d4.z], 1);
            if (v3) p3 = atomicAdd(&cnt[d4.w], 1);
            // consume pass: one wait, then 4 predicated 2B stores
            if (v0 && p0 < ELL_CAP) ell[(size_t)d4.x * ELL_CAP + p0] = (unsigned short)s4.x;
            if (v1 && p1 < ELL_CAP) ell[(size_t)d4.y * ELL_CAP + p1] = (unsigned short)s4.y;
            if (v2 && p2 < ELL_CAP) ell[(size_t)d4.z * ELL_CAP + p2] = (unsigned short)s4.z;
            if (v3 && p3 < ELL_CAP) ell[(size_t)d4.w * ELL_CAP + p3] = (unsigned short)s4.w;
        }
        if (chunk == 0) {                          // E % 4 tail
            for (int e = (E & ~3) + tid; e < E; e += 256) {
                int d = dst[e];
                if (d >= lo && d < hi) {
                    int p = atomicAdd(&cnt[d], 1);
                    if (p < ELL_CAP) ell[(size_t)d * ELL_CAP + p] = (unsigned short)src[e];
                }
            }
        }
        return;
    }

    // ---- gemm1, zero-LDS: B fragments streamed from w1t (32KB, L2-hot) ----
    const int gb = bid - NBUILD;
    const int wave = tid >> 6, lane = tid & 63;
    const int row0 = gb * 64 + wave * 16;
    if (row0 >= n) return;
    const int quad = lane >> 4, l16 = lane & 15;

    short8 af[4];
    {
        const float* arow = x + (size_t)(row0 + l16) * 128 + quad * 8;
        #pragma unroll
        for (int kk = 0; kk < 4; ++kk) {
            float4 u = *(const float4*)(arow + kk * 32);
            float4 v = *(const float4*)(arow + kk * 32 + 4);
            short8 f;
            f[0] = (short)f2bf(u.x); f[1] = (short)f2bf(u.y);
            f[2] = (short)f2bf(u.z); f[3] = (short)f2bf(u.w);
            f[4] = (short)f2bf(v.x); f[5] = (short)f2bf(v.y);
            f[6] = (short)f2bf(v.z); f[7] = (short)f2bf(v.w);
            af[kk] = f;
        }
    }

    #pragma unroll
    for (int t = 0; t < 8; ++t) {
        f32x4 acc = {0.f, 0.f, 0.f, 0.f};
        #pragma unroll
        for (int kk = 0; kk < 4; ++kk) {
            short8 bfr = *(const short8*)(w1t + (t * 16 + l16) * 128 + kk * 32 + quad * 8);
            acc = __builtin_amdgcn_mfma_f32_16x16x32_bf16(af[kk], bfr, acc, 0, 0, 0);
        }
        #pragma unroll
        for (int r = 0; r < 4; ++r) {
            int gr = row0 + quad * 4 + r;
            h1b[(size_t)gr * 128 + t * 16 + l16] = f2bf(acc[r]);   // UNSCALED
        }
    }
}

// ---------------- MFMA GEMM (layer 2, LDS version, unchanged) --------------
// Cb[i][j] = bf16(dinv[i]*(A W)[i][j]); cnt final here.

template<int NC>
__global__ __launch_bounds__(256) void gemm_mfma(
    const short* __restrict__ A, const short* __restrict__ Bt,
    const int* __restrict__ cnt, unsigned short* __restrict__ Cb, int n)
{
    __shared__ short Bs[NC][136];
    const int tid = threadIdx.x;

    #pragma unroll
    for (int i = 0; i < NC / 16; ++i) {
        int idx = tid + i * 256;
        int nrow = idx >> 4;
        int kcol = (idx & 15) * 8;
        *(short8*)&Bs[nrow][kcol] = *(const short8*)(Bt + nrow * 128 + kcol);
    }
    __syncthreads();

    const int wave = tid >> 6, lane = tid & 63;
    const int row0 = blockIdx.x * 64 + wave * 16;
    if (row0 >= n) return;
    const int quad = lane >> 4, l16 = lane & 15;

    short8 af[4];
    {
        const short* arow = A + (size_t)(row0 + l16) * 128 + quad * 8;
        #pragma unroll
        for (int kk = 0; kk < 4; ++kk)
            af[kk] = *(const short8*)(arow + kk * 32);
    }

    float dv[4];
    #pragma unroll
    for (int r = 0; r < 4; ++r)
        dv[r] = rsqrtf((float)cnt[row0 + quad * 4 + r] + 1.0f);

    #pragma unroll
    for (int t = 0; t < NC / 16; ++t) {
        f32x4 acc = {0.f, 0.f, 0.f, 0.f};
        #pragma unroll
        for (int kk = 0; kk < 4; ++kk) {
            short8 bfr = *(const short8*)&Bs[t * 16 + l16][kk * 32 + quad * 8];
            acc = __builtin_amdgcn_mfma_f32_16x16x32_bf16(af[kk], bfr, acc, 0, 0, 0);
        }
        #pragma unroll
        for (int r = 0; r < 4; ++r) {
            int gr = row0 + quad * 4 + r;
            Cb[(size_t)gr * NC + t * 16 + l16] = f2bf(acc[r] * dv[r]);
        }
    }
}

// ---------------- wide-gather aggregates (unchanged) ----------------
// L1: one wave per node, 256B UNSCALED rows, dwordx4 gather = 4 edges/instr.
// MEASURED at 6.2 TB/s effective = gather byte-floor.

__global__ __launch_bounds__(256) void aggregate_l1(
    const unsigned short* __restrict__ hb,   // [n][128] bf16, UNSCALED
    const unsigned short* __restrict__ ell,
    const int* __restrict__ cnt, const float* __restrict__ bias,
    unsigned int* __restrict__ z1b, int n)   // [n][64] bf16x2
{
    const int node = blockIdx.x * 4 + (threadIdx.x >> 6);
    if (node >= n) return;
    const int lane = threadIdx.x & 63;
    const int quad = lane >> 4, l16 = lane & 15;

    int deg = cnt[node];
    const float d = rsqrtf((float)deg + 1.0f);
    if (deg > ELL_CAP) deg = ELL_CAP;
    const unsigned short* __restrict__ row = ell + (size_t)node * ELL_CAP;

    float acc[8];
    {   // self term: q = d on quad 0, else 0 (contributes d^2*h after final *d)
        uint4 v = *(const uint4*)(hb + (size_t)node * 128 + l16 * 8);
        float qs = (quad == 0) ? d : 0.f;
        #pragma unroll
        for (int j = 0; j < 4; ++j) {
            float2 f = bfunpack(((const unsigned int*)&v)[j]);
            acc[2 * j]     = f.x * qs;
            acc[2 * j + 1] = f.y * qs;
        }
    }
    const int degR = (deg + 3) & ~3;
    #pragma unroll 2
    for (int e = 0; e < degR; e += 4) {
        unsigned int w0 = *(const unsigned int*)&row[e];       // edges e,e+1
        unsigned int w1 = *(const unsigned int*)&row[e + 2];   // edges e+2,e+3
        unsigned int hw = (quad & 2) ? w1 : w0;
        int s = (quad & 1) ? (int)(hw >> 16) : (int)(hw & 0xffff);
        s = min(s, n - 1);                                      // poison-safe
        float q = rsqrtf((float)cnt[s] + 1.0f);                 // dinv[src]
        q = (e + quad < deg) ? q : 0.f;                         // 1 cndmask/edge
        uint4 v = *(const uint4*)(hb + (size_t)s * 128 + l16 * 8);
        #pragma unroll
        for (int j = 0; j < 4; ++j) {
            float2 f = bfunpack(((const unsigned int*)&v)[j]);
            acc[2 * j]     = fmaf(f.x, q, acc[2 * j]);
            acc[2 * j + 1] = fmaf(f.y, q, acc[2 * j + 1]);
        }
    }
    #pragma unroll
    for (int j = 0; j < 8; ++j) {            // fold 4 quads
        acc[j] += __shfl_xor(acc[j], 16);
        acc[j] += __shfl_xor(acc[j], 32);
    }
    if (quad == 0) {
        unsigned int ow[4];
        #pragma unroll
        for (int j = 0; j < 4; ++j) {
            float bx = bias[l16 * 8 + 2 * j];
            float by = bias[l16 * 8 + 2 * j + 1];
            float ox = fmaxf(fmaf(acc[2 * j],     d, bx), 0.f);
            float oy = fmaxf(fmaf(acc[2 * j + 1], d, by), 0.f);
            ow[j] = (unsigned int)f2bf(ox) | ((unsigned int)f2bf(oy) << 16);
        }
        *(uint4*)&z1b[(size_t)node * 64 + l16 * 4] = *(const uint4*)ow;
    }
}

// L2: one wave per node, 128B PRE-SCALED rows, dwordx4 gather = 8 edges/instr.

__global__ __launch_bounds__(256) void aggregate_l2(
    const unsigned short* __restrict__ hb,   // [n][64] bf16, dinv-scaled
    const unsigned short* __restrict__ ell,
    const int* __restrict__ cnt, const float* __restrict__ bias,
    float* __restrict__ out, int n)          // [n][64] fp32
{
    const int node = blockIdx.x * 4 + (threadIdx.x >> 6);
    if (node >= n) return;
    const int lane = threadIdx.x & 63;
    const int oct = lane >> 3, l8 = lane & 7;

    int deg = cnt[node];
    const float d = rsqrtf((float)deg + 1.0f);
    if (deg > ELL_CAP) deg = ELL_CAP;
    const unsigned short* __restrict__ row = ell + (size_t)node * ELL_CAP;

    float acc[8];
    {   // self term (oct 0 only)
        uint4 v = *(const uint4*)(hb + (size_t)node * 64 + l8 * 8);
        float ms = (oct == 0) ? 1.f : 0.f;
        #pragma unroll
        for (int j = 0; j < 4; ++j) {
            float2 f = bfunpack(((const unsigned int*)&v)[j]);
            acc[2 * j]     = f.x * ms;
            acc[2 * j + 1] = f.y * ms;
        }
    }
    const int degR = (deg + 7) & ~7;
    #pragma unroll 2
    for (int e = 0; e < degR; e += 8) {
        uint4 w = *(const uint4*)&row[e];    // edges e..e+7
        unsigned int pw = (oct & 4) ? ((oct & 2) ? w.w : w.z)
                                    : ((oct & 2) ? w.y : w.x);
        int s = (oct & 1) ? (int)(pw >> 16) : (int)(pw & 0xffff);
        s = min(s, n - 1);                   // poison-safe
        float m = (e + oct < deg) ? 1.f : 0.f;   // 1 cndmask/edge
        uint4 v = *(const uint4*)(hb + (size_t)s * 64 + l8 * 8);
        #pragma unroll
        for (int j = 0; j < 4; ++j) {
            float2 f = bfunpack(((const unsigned int*)&v)[j]);
            acc[2 * j]     = fmaf(f.x, m, acc[2 * j]);
            acc[2 * j + 1] = fmaf(f.y, m, acc[2 * j + 1]);
        }
    }
    #pragma unroll
    for (int j = 0; j < 8; ++j) {            // fold 8 octs
        acc[j] += __shfl_xor(acc[j], 8);
        acc[j] += __shfl_xor(acc[j], 16);
        acc[j] += __shfl_xor(acc[j], 32);
    }
    if (oct == 0) {
        float* op = out + (size_t)node * 64 + l8 * 8;
        float4 o0, o1;
        o0.x = fmaf(acc[0], d, bias[l8 * 8 + 0]);
        o0.y = fmaf(acc[1], d, bias[l8 * 8 + 1]);
        o0.z = fmaf(acc[2], d, bias[l8 * 8 + 2]);
        o0.w = fmaf(acc[3], d, bias[l8 * 8 + 3]);
        o1.x = fmaf(acc[4], d, bias[l8 * 8 + 4]);
        o1.y = fmaf(acc[5], d, bias[l8 * 8 + 5]);
        o1.z = fmaf(acc[6], d, bias[l8 * 8 + 6]);
        o1.w = fmaf(acc[7], d, bias[l8 * 8 + 7]);
        *(float4*)(op)     = o0;
        *(float4*)(op + 4) = o1;
    }
}

// ---------------- launcher ----------------

extern "C" void kernel_launch(void* const* d_in, const int* in_sizes, int n_in,
                              void* d_out, int out_size, void* d_ws, size_t ws_size,
                              hipStream_t stream)
{
    const float* x  = (const float*)d_in[0];
    const int*   ei = (const int*)d_in[1];   // [2][E] int32
    const float* W1 = (const float*)d_in[2];
    const float* b1 = (const float*)d_in[3];
    const float* W2 = (const float*)d_in[4];
    const float* b2 = (const float*)d_in[5];
    float* out = (float*)d_out;

    const int N = in_sizes[0] / 128;   // 50000
    const int E = in_sizes[1] / 2;     // 800000
    const int* src = ei;
    const int* dst = ei + E;
    const int partSize = (N + NPART - 1) / NPART;   // 6250

    char* ws = (char*)d_ws;
    size_t off = 0;
    auto alloc = [&](size_t bytes) -> void* {
        void* p = ws + off;
        off += (bytes + 255) & ~(size_t)255;
        return p;
    };
    int*            cnt  = (int*)           alloc((size_t)N * 4);
    unsigned short* ell  = (unsigned short*)alloc((size_t)N * ELL_CAP * 2);
    short*          w1t  = (short*)         alloc((size_t)128 * 128 * 2);
    short*          w2t  = (short*)         alloc((size_t)64 * 128 * 2);
    unsigned short* h1b  = (unsigned short*)alloc((size_t)N * 128 * 2);  // bf16
    unsigned int*   z1b  = (unsigned int*)  alloc((size_t)N * 64 * 4);   // bf16x2
    unsigned short* h2b  = (unsigned short*)alloc((size_t)N * 64 * 2);   // bf16

    init_misc<<<(N + 255) / 256, 256, 0, stream>>>(W1, W2, w1t, w2t, cnt, N);

    // XCD-partitioned build (blocks first) + zero-LDS gemm1 tail
    const int nGemm = (N + 63) / 64;               // 782
    fused_b_g1<<<NBUILD + nGemm, 256, 0, stream>>>(
        x, w1t, src, dst, cnt, ell, h1b, N, E, partSize);

    aggregate_l1<<<(N + 3) / 4, 256, 0, stream>>>(h1b, ell, cnt, b1, z1b, N);

    gemm_mfma<64><<<(N + 63) / 64, 256, 0, stream>>>(
        (const short*)z1b, w2t, cnt, h2b, N);

    aggregate_l2<<<(N + 3) / 4, 256, 0, stream>>>(h2b, ell, cnt, b2, out, N);
}